// Round 6
// baseline (1608.069 us; speedup 1.0000x reference)
//
#include <hip/hip_runtime.h>
#include <stdint.h>

typedef unsigned short u16;
typedef __bf16 bf16x8 __attribute__((ext_vector_type(8)));
typedef float floatx4 __attribute__((ext_vector_type(4)));

#define HIDDEN 2560
#define NHEADS 32
#define HD 80
#define SEQ 2048
#define BATCH 2
#define MROWS (BATCH*SEQ)
#define QB 64

__device__ __forceinline__ float bf2f(uint32_t bits) {
    return __uint_as_float(bits << 16);
}
__device__ __forceinline__ u16 f2bf_bits(float f) {
    uint32_t x = __float_as_uint(f);
    uint32_t r = (x + 0x7fffu + ((x >> 16) & 1u)) >> 16;  // RTNE
    return (u16)r;
}
__device__ __forceinline__ floatx4 mk4(float x) {
    return (floatx4){x, x, x, x};
}
__device__ __forceinline__ floatx4 exp4(floatx4 a) {
    floatx4 r;
#pragma unroll
    for (int i = 0; i < 4; i++) r[i] = __expf(a[i]);
    return r;
}
// async global->LDS, 16B per lane; dest is wave-uniform base + lane*16 (linear)
__device__ __forceinline__ void gload16(const u16* g, u16* l) {
    __builtin_amdgcn_global_load_lds(
        (const __attribute__((address_space(1))) uint32_t*)g,
        (__attribute__((address_space(3))) uint32_t*)l, 16, 0, 0);
}

// ---------------- split fp32 -> bf16 hi/lo, elementwise (optional scale) ---------
__global__ __launch_bounds__(256) void split_x(const float* __restrict__ in,
                                               u16* __restrict__ hi,
                                               u16* __restrict__ lo,
                                               float scale) {
    size_t i4 = (size_t)blockIdx.x * 256 + threadIdx.x;
    float4 v = ((const float4*)in)[i4];
    float f[4] = {v.x * scale, v.y * scale, v.z * scale, v.w * scale};
    u16 h[4], l[4];
#pragma unroll
    for (int j = 0; j < 4; j++) {
        h[j] = f2bf_bits(f[j]);
        l[j] = f2bf_bits(f[j] - bf2f(h[j]));
    }
    ((uint2*)hi)[i4] = *(uint2*)h;
    ((uint2*)lo)[i4] = *(uint2*)l;
}

// ------------- transpose + split: W[k][n] fp32 -> WT hi/lo bf16 [n][k] ------------
__global__ __launch_bounds__(256) void split_wt(const float* __restrict__ in,
                                                u16* __restrict__ outh,
                                                u16* __restrict__ outl) {
    __shared__ float t[64][65];
    int k0 = blockIdx.x * 64;
    int n0 = blockIdx.y * 64;
    int tid = threadIdx.x;
    int rr = tid >> 4;
    int c4 = (tid & 15) * 4;
#pragma unroll
    for (int it = 0; it < 4; it++) {
        int row = it * 16 + rr;
        float4 v = *(const float4*)&in[(size_t)(k0 + row) * HIDDEN + n0 + c4];
        t[row][c4 + 0] = v.x; t[row][c4 + 1] = v.y;
        t[row][c4 + 2] = v.z; t[row][c4 + 3] = v.w;
    }
    __syncthreads();
#pragma unroll
    for (int it = 0; it < 4; it++) {
        int row = it * 16 + rr;
        float f[4] = { t[c4 + 0][row], t[c4 + 1][row], t[c4 + 2][row], t[c4 + 3][row] };
        u16 h[4], l[4];
#pragma unroll
        for (int j = 0; j < 4; j++) {
            h[j] = f2bf_bits(f[j]);
            l[j] = f2bf_bits(f[j] - bf2f(h[j]));
        }
        size_t o = (size_t)(n0 + row) * HIDDEN + k0 + c4;
        *(uint2*)&outh[o] = *(uint2*)h;
        *(uint2*)&outl[o] = *(uint2*)l;
    }
}

// ------- GEMM: C[M][N] = A[M][K] * Bt[N][K]^T, pre-split bf16 in, fp32 out --------
// v4: A staged via global_load_lds into a 2x16KB LDS double buffer (single
// barrier per K-step); B FRAGMENTS READ DIRECTLY FROM GLOBAL (weights are
// L2/L3-resident) — halves LDS read traffic (49 -> 98 FLOP/LDS-byte, was the
// structural cap) and halves LDS footprint. XCD-aware block swizzle.
__global__ __launch_bounds__(256) void gemm_bt2(const u16* __restrict__ Ah,
                                                const u16* __restrict__ Al,
                                                const u16* __restrict__ Bh,
                                                const u16* __restrict__ Bl,
                                                float* __restrict__ C) {
    __shared__ u16 lds[2 * 8192];     // 32768 B: buf x {Ah,Al} x [128][32]
    const int K = HIDDEN;
    int tid  = threadIdx.x;
    int lane = tid & 63;
    int wave = tid >> 6;
    int wr = wave >> 1, wc = wave & 1;
    int lr = lane & 15, lq = lane >> 4;

    // XCD-aware swizzle of dispatch-linear block id
    int nwgx = gridDim.x;                               // 20
    int orig = blockIdx.y * nwgx + blockIdx.x;
    int cpx  = (nwgx * gridDim.y) >> 3;                 // 80
    int wg   = (orig & 7) * cpx + (orig >> 3);
    int n0 = (wg % nwgx) * 128, m0 = (wg / nwgx) * 128;

    int srow = wave * 32 + (lane >> 2);
    int scol = ((lane & 3) ^ ((lane >> 3) & 3)) * 8;
    const u16* gAh = Ah + (size_t)(m0 + srow) * K + scol;
    const u16* gAl = Al + (size_t)(m0 + srow) * K + scol;
    const size_t q1 = (size_t)16 * K;
    int dso = wave * 1024;                              // staging dest base (u16)

    // per-lane direct B fragment pointers: row (C col) = n0+wc*64+j*16+lr,
    // k = k0 + lq*8 .. +7  (16B aligned; lanes {lr,+16,+32,+48} coalesce to 64B)
    const u16* gBh = Bh + (size_t)(n0 + wc * 64 + lr) * K + lq * 8;
    const u16* gBl = Bl + (size_t)(n0 + wc * 64 + lr) * K + lq * 8;

    floatx4 acc[4][4];
#pragma unroll
    for (int i = 0; i < 4; i++)
#pragma unroll
        for (int j = 0; j < 4; j++)
            acc[i][j] = mk4(0.f);

    int swz = (lr >> 1) & 3;
    int rsl = (lq ^ swz) * 8;

    auto stage = [&](int k0, int bsel) {
        u16* Bf = lds + bsel * 8192 + dso;
        gload16(gAh + k0, Bf);          gload16(gAh + q1 + k0, Bf + 512);
        gload16(gAl + k0, Bf + 4096);   gload16(gAl + q1 + k0, Bf + 4608);
    };

    const int NT = K / 32;                              // 80
    stage(0, 0);
    for (int t = 0; t < NT; t++) {
        int k0 = t * 32;
        __syncthreads();               // drains vmcnt(0): A buf[t&1] ready; WAR safe
        // B fragments direct from global (separate pipe; latency hidden by TLP)
        bf16x8 bh[4], bl[4];
#pragma unroll
        for (int j = 0; j < 4; j++) {
            bh[j] = *(const bf16x8*)&gBh[(size_t)j * 16 * K + k0];
            bl[j] = *(const bf16x8*)&gBl[(size_t)j * 16 * K + k0];
        }
        if (t + 1 < NT) stage(k0 + 32, (t + 1) & 1);
        u16* Bc = lds + (t & 1) * 8192;
        bf16x8 ah[4], al[4];
#pragma unroll
        for (int i = 0; i < 4; i++) {
            int ra = (wr * 64 + i * 16 + lr) * 32 + rsl;
            ah[i] = *(const bf16x8*)&Bc[ra];
            al[i] = *(const bf16x8*)&Bc[4096 + ra];
        }
#pragma unroll
        for (int i = 0; i < 4; i++)
#pragma unroll
            for (int j = 0; j < 4; j++) {
                acc[i][j] = __builtin_amdgcn_mfma_f32_16x16x32_bf16(ah[i], bh[j], acc[i][j], 0, 0, 0);
                acc[i][j] = __builtin_amdgcn_mfma_f32_16x16x32_bf16(ah[i], bl[j], acc[i][j], 0, 0, 0);
                acc[i][j] = __builtin_amdgcn_mfma_f32_16x16x32_bf16(al[i], bh[j], acc[i][j], 0, 0, 0);
            }
    }
#pragma unroll
    for (int i = 0; i < 4; i++) {
        int rowb = m0 + wr * 64 + i * 16 + lq * 4;
#pragma unroll
        for (int j = 0; j < 4; j++) {
            int col = n0 + wc * 64 + j * 16 + lr;
#pragma unroll
            for (int r = 0; r < 4; r++)
                C[(size_t)(rowb + r) * HIDDEN + col] = acc[i][j][r];
        }
    }
}

// ---------------- RoPE (ROT=20 -> 10 pairs) on Q and K, in place, fp32 -----------
__global__ __launch_bounds__(256) void rope_k(float* __restrict__ Qb, float* __restrict__ Kb,
                                              const int* __restrict__ pos_ids) {
    int idx = blockIdx.x * 256 + threadIdx.x;
    int row = idx >> 5;
    int h   = idx & 31;
    float pos = (float)pos_ids[row];
    size_t base = (size_t)row * HIDDEN + h * HD;
    float* q = Qb + base;
    float* k = Kb + base;
#pragma unroll
    for (int i = 0; i < 10; i++) {
        float freq = pos * exp2f(-1.3287712379549449f * (float)i);
        float sn, cs;
        sincosf(freq, &sn, &cs);
        float q1 = q[i], q2 = q[i + 10];
        q[i]      = q1 * cs - q2 * sn;
        q[i + 10] = q2 * cs + q1 * sn;
        float k1 = k[i], k2 = k[i + 10];
        k[i]      = k1 * cs - k2 * sn;
        k[i + 10] = k2 * cs + k1 * sn;
    }
}

// ---- V transpose+split: Vb fp32 -> Vth/Vtl u16 [bh][d(80)][key*(2048)]
// key* layout: within each 32-key tile, col 8a+4h+j holds key 16h+4a+j
// (so the PV A-fragment's k-slot order lq*8+{0..7} = keys {4lq..4lq+3, 16+4lq..+3}
//  matches the lane-local p-values after swapped QK^T — no P shuffle needed).
__global__ __launch_bounds__(256) void vtrans(const float* __restrict__ Vb,
                                              u16* __restrict__ Vth,
                                              u16* __restrict__ Vtl) {
    __shared__ float t[64][81];
    int bh = blockIdx.x; int b = bh >> 5, h = bh & 31;
    int s0 = blockIdx.y * 64;
    int tid = threadIdx.x;
    for (int idx = tid; idx < 64 * 20; idx += 256) {
        int s = idx / 20, c = idx % 20;
        float4 v = *(const float4*)&Vb[(size_t)(b * SEQ + s0 + s) * HIDDEN + h * HD + c * 4];
        t[s][c * 4 + 0] = v.x; t[s][c * 4 + 1] = v.y;
        t[s][c * 4 + 2] = v.z; t[s][c * 4 + 3] = v.w;
    }
    __syncthreads();
    for (int idx = tid; idx < 80 * 16; idx += 256) {   // 4-key chunks
        int d = idx >> 4, ch = idx & 15;
        int t2 = ch >> 3, e = ch & 7, a = e >> 1, h2 = e & 1;
        int srck = t2 * 32 + 16 * h2 + 4 * a;
        int dstc = t2 * 32 + 8 * a + 4 * h2;
        u16 hh[4], ll[4];
#pragma unroll
        for (int j = 0; j < 4; j++) {
            float f = t[srck + j][d];
            hh[j] = f2bf_bits(f);
            ll[j] = f2bf_bits(f - bf2f(hh[j]));
        }
        size_t o = ((size_t)bh * HD + d) * SEQ + s0 + dstc;
        *(uint2*)&Vth[o] = *(uint2*)hh;
        *(uint2*)&Vtl[o] = *(uint2*)ll;
    }
}

// ---------------- MFMA flash attention, v4 (QB=64: 4 waves x 16 queries) ---------
// 64 queries/block; wave w owns queries [q0+16w, q0+16w+16). 32-key tiles,
// double-buffered, single barrier per tile, staging via global_load_lds
// (w0=Kh, w1=Kl, w2=Vh, w3=Vl; 5 calls each). S^T = mfma(K, Q): lane holds
// q = lane&15, keys {lq*4+r, 16+lq*4+r}. Softmax per-lane scalar + 2 shfl_xor;
// P packed to bf16 in-register (key-interleaved V). Q pre-scaled by 1/sqrt(HD).
__global__ __launch_bounds__(256, 4) void attn_mfma(const u16* __restrict__ Qh_,
                                                 const u16* __restrict__ Ql_,
                                                 const u16* __restrict__ Kh_,
                                                 const u16* __restrict__ Kl_,
                                                 const u16* __restrict__ Vth_,
                                                 const u16* __restrict__ Vtl_,
                                                 u16* __restrict__ Oh_,
                                                 u16* __restrict__ Ol_) {
    __shared__ u16 lds[20480];          // 2 x 10240 u16 tile buffers = 40960 B

    int tid = threadIdx.x;
    int lane = tid & 63, w = tid >> 6;
    int lr = lane & 15, lq = lane >> 4;
    int bh = blockIdx.x; int b = bh >> 5, h = bh & 31;
    int qblk = (gridDim.y - 1) - blockIdx.y;   // long blocks dispatched first
    int q0 = qblk * QB;
    size_t rowbase = (size_t)b * SEQ;
    size_t hoff = (size_t)h * HD;

    // ---- stage Q (64 rows, hi @0 / lo @6656, pitch 104) -> B-frags ----
    bf16x8 qh[2], ql[2], qta;
    for (int idx = tid; idx < 1280; idx += 256) {
        int buf = idx >= 640; int e = idx - buf * 640;
        int r = e / 10, c = e % 10;
        const u16* src = (buf ? Ql_ : Qh_) +
            (rowbase + q0 + r) * HIDDEN + hoff + c * 8;
        *(int4*)&lds[buf * 6656 + r * 104 + c * 8] = *(const int4*)src;
    }
    __syncthreads();
    {
        int tba = (lq >> 1) ? 6656 : 0;      // qta: lq<2 -> Qh else Ql
        int tcol = 64 + (lq & 1) * 8;
        int lrow = w * 16 + lr;
#pragma unroll
        for (int c = 0; c < 2; c++) {
            qh[c] = *(const bf16x8*)&lds[lrow * 104 + c * 32 + lq * 8];
            ql[c] = *(const bf16x8*)&lds[6656 + lrow * 104 + c * 32 + lq * 8];
        }
        qta = *(const bf16x8*)&lds[tba + lrow * 104 + tcol];
    }
    __syncthreads();

    floatx4 acc[5];
    float mrow = -3.0e38f, lsum = 0.f;
#pragma unroll
    for (int nt = 0; nt < 5; nt++) acc[nt] = mk4(0.f);

    int ntiles = 2 * qblk + 2;
    int qw0 = q0 + w * 16;

    // per-lane staging address components (element units)
    int k0RowOff = (lane >> 3) * HIDDEN + (((lane & 7) ^ (lane >> 3)) * 8);
    int k1RowOff = (lane >> 1) * HIDDEN + 64 + (lane & 1) * 8;
    int vRowOff  = (lane >> 2) * SEQ + ((((lane & 3) ^ ((lane >> 3) & 3))) * 8);
    const u16* kSrc = (w & 1 ? Kl_ : Kh_) + rowbase * HIDDEN + hoff;
    const u16* vSrc = (w == 3 ? Vtl_ : Vth_) + (size_t)bh * HD * SEQ;

    auto stage = [&](int t, int bsel) {
        int k0 = t * 32;
        u16* B = lds + bsel * 10240;
        if (w < 2) {
            const u16* kb = kSrc + (size_t)k0 * HIDDEN;
            u16* d0 = B + w * 2048;
#pragma unroll
            for (int j = 0; j < 4; j++)
                gload16(kb + (size_t)j * 8 * HIDDEN + k0RowOff, d0 + j * 512);
            gload16(kb + k1RowOff, B + 4096 + w * 512);
        } else {
            const u16* vb = vSrc + k0;
            u16* d0 = B + 5120 + (w == 3 ? 2560 : 0);
#pragma unroll
            for (int j = 0; j < 5; j++)
                gload16(vb + (size_t)j * 16 * SEQ + vRowOff, d0 + j * 512);
        }
    };

    // read-side swizzle constants (thread-invariant)
    int ks0 = ((lq) ^ (lr & 7)) * 8;          // K0 c=0 slot
    int ks1 = ((4 + lq) ^ (lr & 7)) * 8;      // K0 c=1 slot
    int k1off  = (lq >> 1) * 512 + (lq & 1) * 8;          // [Kh|Kl] variant
    int k1offb = ((lq >> 1) ^ 1) * 512 + (lq & 1) * 8;    // [Kl|Kh] variant
    int vsl = (lq ^ ((lr >> 1) & 3)) * 8;

    stage(0, 0);

    for (int t = 0; t < ntiles; t++) {
        int k0 = t * 32;
        __syncthreads();                         // drains vmcnt(0): tile t ready
        if (t + 1 < ntiles) stage(t + 1, (t + 1) & 1);
        u16* B = lds + (t & 1) * 10240;
        if (k0 <= qw0 + 15) {
            u16* bK0h = B;
            u16* bK0l = B + 2048;
            u16* bK1  = B + 4096;
            u16* bVh  = B + 5120;
            u16* bVl  = B + 7680;
            __builtin_amdgcn_s_setprio(1);
            // ---- S^T = K Q^T (A=K frag, B=Q frag) ----
            floatx4 s[2];
#pragma unroll
            for (int st = 0; st < 2; st++) {
                int krow = st * 16 + lr;
                bf16x8 kh0 = *(const bf16x8*)&bK0h[krow * 64 + ks0];
                bf16x8 kh1 = *(const bf16x8*)&bK0h[krow * 64 + ks1];
                bf16x8 kl0 = *(const bf16x8*)&bK0l[krow * 64 + ks0];
                bf16x8 kl1 = *(const bf16x8*)&bK0l[krow * 64 + ks1];
                bf16x8 k1f  = *(const bf16x8*)&bK1[krow * 16 + k1off];
                bf16x8 k1fb = *(const bf16x8*)&bK1[krow * 16 + k1offb];
                floatx4 sv = mk4(0.f);
                sv = __builtin_amdgcn_mfma_f32_16x16x32_bf16(kh0, qh[0], sv, 0, 0, 0);
                sv = __builtin_amdgcn_mfma_f32_16x16x32_bf16(kl0, qh[0], sv, 0, 0, 0);
                sv = __builtin_amdgcn_mfma_f32_16x16x32_bf16(kh0, ql[0], sv, 0, 0, 0);
                sv = __builtin_amdgcn_mfma_f32_16x16x32_bf16(kh1, qh[1], sv, 0, 0, 0);
                sv = __builtin_amdgcn_mfma_f32_16x16x32_bf16(kl1, qh[1], sv, 0, 0, 0);
                sv = __builtin_amdgcn_mfma_f32_16x16x32_bf16(kh1, ql[1], sv, 0, 0, 0);
                sv = __builtin_amdgcn_mfma_f32_16x16x32_bf16(k1f,  qta, sv, 0, 0, 0);
                sv = __builtin_amdgcn_mfma_f32_16x16x32_bf16(k1fb, qta, sv, 0, 0, 0);
                s[st] = sv;
            }
            // ---- causal mask (lane q = qw0+lr; keys k0+st*16+lq*4+r) ----
            if (k0 + 31 > qw0) {
                int qmy = qw0 + lr - k0 - lq * 4;   // key_local = st*16+r
#pragma unroll
                for (int r = 0; r < 4; r++) {
                    s[0][r] = (r <= qmy)      ? s[0][r] : -3.0e38f;
                    s[1][r] = (16 + r <= qmy) ? s[1][r] : -3.0e38f;
                }
            }
            // ---- online softmax (per-lane scalar, reduce over lq groups) ----
            float rm = fmaxf(fmaxf(fmaxf(s[0][0], s[0][1]), fmaxf(s[0][2], s[0][3])),
                             fmaxf(fmaxf(s[1][0], s[1][1]), fmaxf(s[1][2], s[1][3])));
            rm = fmaxf(rm, __shfl_xor(rm, 16));
            rm = fmaxf(rm, __shfl_xor(rm, 32));
            int need = rm > mrow + 8.f;
            if (__any(need)) {                 // rescale path (rare: defer-max)
                float mnew = fmaxf(mrow, rm);
                float alpha = __expf(mrow - mnew);
                mrow = mnew;
                lsum *= alpha;
                float at[4];
#pragma unroll
                for (int r = 0; r < 4; r++) at[r] = __shfl(alpha, lq * 4 + r);
#pragma unroll
                for (int nt = 0; nt < 5; nt++)
#pragma unroll
                    for (int r = 0; r < 4; r++) acc[nt][r] *= at[r];
            }
            floatx4 p0 = exp4(s[0] - mk4(mrow));
            floatx4 p1 = exp4(s[1] - mk4(mrow));
            floatx4 ps = p0 + p1;
            float rs = ps[0] + ps[1] + ps[2] + ps[3];
            rs += __shfl_xor(rs, 16);
            rs += __shfl_xor(rs, 32);
            lsum += rs;
            // ---- pack P in-register (matches key-interleaved V layout) ----
            bf16x8 pa;
            pa[0] = (__bf16)p0[0]; pa[1] = (__bf16)p0[1];
            pa[2] = (__bf16)p0[2]; pa[3] = (__bf16)p0[3];
            pa[4] = (__bf16)p1[0]; pa[5] = (__bf16)p1[1];
            pa[6] = (__bf16)p1[2]; pa[7] = (__bf16)p1[3];
            // ---- O += P V ----
#pragma unroll
            for (int nt = 0; nt < 5; nt++) {
                bf16x8 vh = *(const bf16x8*)&bVh[(nt * 16 + lr) * 32 + vsl];
                bf16x8 vl = *(const bf16x8*)&bVl[(nt * 16 + lr) * 32 + vsl];
                acc[nt] = __builtin_amdgcn_mfma_f32_16x16x32_bf16(pa, vh, acc[nt], 0, 0, 0);
                acc[nt] = __builtin_amdgcn_mfma_f32_16x16x32_bf16(pa, vl, acc[nt], 0, 0, 0);
            }
            __builtin_amdgcn_s_setprio(0);
        }
    }
    // ---- epilogue: O /= l, write split-bf16 ----
    {
        float il = 1.f / lsum;
        float inv[4];
#pragma unroll
        for (int r = 0; r < 4; r++) inv[r] = __shfl(il, lq * 4 + r);
#pragma unroll
        for (int nt = 0; nt < 5; nt++) {
#pragma unroll
            for (int r = 0; r < 4; r++) {
                float o = acc[nt][r] * inv[r];
                u16 hh = f2bf_bits(o);
                u16 ll = f2bf_bits(o - bf2f(hh));
                size_t row = rowbase + qw0 + lq * 4 + r;
                Oh_[row * HIDDEN + hoff + nt * 16 + lr] = hh;
                Ol_[row * HIDDEN + hoff + nt * 16 + lr] = ll;
            }
        }
    }
}

extern "C" void kernel_launch(void* const* d_in, const int* in_sizes, int n_in,
                              void* d_out, int out_size, void* d_ws, size_t ws_size,
                              hipStream_t stream) {
    const float* hidden = (const float*)d_in[0];
    const int* pos    = (const int*)d_in[2];
    const float* Wq   = (const float*)d_in[3];
    const float* Wk   = (const float*)d_in[4];
    const float* Wv   = (const float*)d_in[5];
    const float* Wo   = (const float*)d_in[6];

    const size_t NQ = (size_t)MROWS * HIDDEN;          // 10,485,760 elems
    float* ws = (float*)d_ws;
    float* Qb = ws;                                     // [0, NQ) fp32
    float* Kb = ws + NQ;                                // [NQ, 2NQ) fp32
    float* Vb = ws + 2 * NQ;                            // [2NQ, 3NQ) fp32
    u16* Ah  = (u16*)(ws + 3 * NQ);                     // NQ u16
    u16* Al  = Ah + NQ;                                 // NQ u16
    u16* WTh = Al + NQ;                                 // 2560^2 u16
    u16* WTl = WTh + (size_t)HIDDEN * HIDDEN;           // 2560^2 u16
    u16* Vth = Ah;                    // after QKV GEMMs, Ah/Al free
    u16* Vtl = Al;
    u16* Qh  = (u16*)Vb;              // after vtrans, Vb free
    u16* Ql  = Qh + NQ;
    u16* Kh  = (u16*)Qb;              // after Q split, Qb free
    u16* Kl  = Kh + NQ;
    u16* Oh  = (u16*)Kb;              // after K split, Kb free
    u16* Ol  = Oh + NQ;

    const float SC = 0.11180339887498949f;              // 1/sqrt(80)

    dim3 blk(256);
    dim3 wgrid(HIDDEN / 64, HIDDEN / 64);
    dim3 ggrid(HIDDEN / 128, MROWS / 128);

    split_x<<<dim3(NQ / 1024), blk, 0, stream>>>(hidden, Ah, Al, 1.f);
    split_wt<<<wgrid, blk, 0, stream>>>(Wq, WTh, WTl);
    gemm_bt2<<<ggrid, blk, 0, stream>>>(Ah, Al, WTh, WTl, Qb);
    split_wt<<<wgrid, blk, 0, stream>>>(Wk, WTh, WTl);
    gemm_bt2<<<ggrid, blk, 0, stream>>>(Ah, Al, WTh, WTl, Kb);
    split_wt<<<wgrid, blk, 0, stream>>>(Wv, WTh, WTl);
    gemm_bt2<<<ggrid, blk, 0, stream>>>(Ah, Al, WTh, WTl, Vb);
    rope_k<<<dim3(MROWS * NHEADS / 256), blk, 0, stream>>>(Qb, Kb, pos);
    vtrans<<<dim3(BATCH * NHEADS, SEQ / 64), blk, 0, stream>>>(Vb, Vth, Vtl);
    split_x<<<dim3(NQ / 1024), blk, 0, stream>>>(Qb, Qh, Ql, SC);
    split_x<<<dim3(NQ / 1024), blk, 0, stream>>>(Kb, Kh, Kl, 1.f);
    attn_mfma<<<dim3(BATCH * NHEADS, SEQ / QB), blk, 0, stream>>>(Qh, Ql, Kh, Kl,
                                                                  Vth, Vtl, Oh, Ol);
    split_wt<<<wgrid, blk, 0, stream>>>(Wo, WTh, WTl);
    gemm_bt2<<<ggrid, blk, 0, stream>>>(Oh, Ol, WTh, WTl, (float*)d_out);
}

// Round 7
// 1137.585 us; speedup vs baseline: 1.4136x; 1.4136x over previous
//
#include <hip/hip_runtime.h>
#include <stdint.h>

typedef unsigned short u16;
typedef __bf16 bf16x8 __attribute__((ext_vector_type(8)));
typedef float floatx4 __attribute__((ext_vector_type(4)));

#define HIDDEN 2560
#define NHEADS 32
#define HD 80
#define SEQ 2048
#define BATCH 2
#define MROWS (BATCH*SEQ)
#define QB 64

__device__ __forceinline__ float bf2f(uint32_t bits) {
    return __uint_as_float(bits << 16);
}
__device__ __forceinline__ u16 f2bf_bits(float f) {
    uint32_t x = __float_as_uint(f);
    uint32_t r = (x + 0x7fffu + ((x >> 16) & 1u)) >> 16;  // RTNE
    return (u16)r;
}
__device__ __forceinline__ floatx4 mk4(float x) {
    return (floatx4){x, x, x, x};
}
__device__ __forceinline__ floatx4 exp4(floatx4 a) {
    floatx4 r;
#pragma unroll
    for (int i = 0; i < 4; i++) r[i] = __expf(a[i]);
    return r;
}
// async global->LDS, 16B per lane; dest is wave-uniform base + lane*16 (linear)
__device__ __forceinline__ void gload16(const u16* g, u16* l) {
    __builtin_amdgcn_global_load_lds(
        (const __attribute__((address_space(1))) uint32_t*)g,
        (__attribute__((address_space(3))) uint32_t*)l, 16, 0, 0);
}

// ---------------- split fp32 -> bf16 hi/lo, elementwise (optional scale) ---------
__global__ __launch_bounds__(256) void split_x(const float* __restrict__ in,
                                               u16* __restrict__ hi,
                                               u16* __restrict__ lo,
                                               float scale) {
    size_t i4 = (size_t)blockIdx.x * 256 + threadIdx.x;
    float4 v = ((const float4*)in)[i4];
    float f[4] = {v.x * scale, v.y * scale, v.z * scale, v.w * scale};
    u16 h[4], l[4];
#pragma unroll
    for (int j = 0; j < 4; j++) {
        h[j] = f2bf_bits(f[j]);
        l[j] = f2bf_bits(f[j] - bf2f(h[j]));
    }
    ((uint2*)hi)[i4] = *(uint2*)h;
    ((uint2*)lo)[i4] = *(uint2*)l;
}

// ------------- transpose + split: W[k][n] fp32 -> WT hi/lo bf16 [n][k] ------------
__global__ __launch_bounds__(256) void split_wt(const float* __restrict__ in,
                                                u16* __restrict__ outh,
                                                u16* __restrict__ outl) {
    __shared__ float t[64][65];
    int k0 = blockIdx.x * 64;
    int n0 = blockIdx.y * 64;
    int tid = threadIdx.x;
    int rr = tid >> 4;
    int c4 = (tid & 15) * 4;
#pragma unroll
    for (int it = 0; it < 4; it++) {
        int row = it * 16 + rr;
        float4 v = *(const float4*)&in[(size_t)(k0 + row) * HIDDEN + n0 + c4];
        t[row][c4 + 0] = v.x; t[row][c4 + 1] = v.y;
        t[row][c4 + 2] = v.z; t[row][c4 + 3] = v.w;
    }
    __syncthreads();
#pragma unroll
    for (int it = 0; it < 4; it++) {
        int row = it * 16 + rr;
        float f[4] = { t[c4 + 0][row], t[c4 + 1][row], t[c4 + 2][row], t[c4 + 3][row] };
        u16 h[4], l[4];
#pragma unroll
        for (int j = 0; j < 4; j++) {
            h[j] = f2bf_bits(f[j]);
            l[j] = f2bf_bits(f[j] - bf2f(h[j]));
        }
        size_t o = (size_t)(n0 + row) * HIDDEN + k0 + c4;
        *(uint2*)&outh[o] = *(uint2*)h;
        *(uint2*)&outl[o] = *(uint2*)l;
    }
}

// ------- GEMM: C[M][N] = A[M][K] * Bt[N][K]^T, pre-split bf16 in, fp32 out --------
// Round-5 structure (measured 190us): double-buffered LDS (2 x 32KB), single
// barrier per K-step, stage(t+1) before compute(t); XCD-aware block swizzle.
__global__ __launch_bounds__(256) void gemm_bt2(const u16* __restrict__ Ah,
                                                const u16* __restrict__ Al,
                                                const u16* __restrict__ Bh,
                                                const u16* __restrict__ Bl,
                                                float* __restrict__ C) {
    __shared__ u16 lds[2 * 16384];     // 65536 B: buf x {Ah,Al,Bh,Bl} x [128][32]
    const int K = HIDDEN;
    int tid  = threadIdx.x;
    int lane = tid & 63;
    int wave = tid >> 6;
    int wr = wave >> 1, wc = wave & 1;
    int lr = lane & 15, lq = lane >> 4;

    int nwgx = gridDim.x;                               // 20
    int orig = blockIdx.y * nwgx + blockIdx.x;
    int cpx  = (nwgx * gridDim.y) >> 3;                 // 80
    int wg   = (orig & 7) * cpx + (orig >> 3);
    int n0 = (wg % nwgx) * 128, m0 = (wg / nwgx) * 128;

    int srow = wave * 32 + (lane >> 2);
    int scol = ((lane & 3) ^ ((lane >> 3) & 3)) * 8;
    const u16* gAh = Ah + (size_t)(m0 + srow) * K + scol;
    const u16* gAl = Al + (size_t)(m0 + srow) * K + scol;
    const u16* gBh = Bh + (size_t)(n0 + srow) * K + scol;
    const u16* gBl = Bl + (size_t)(n0 + srow) * K + scol;
    const size_t q1 = (size_t)16 * K;
    int dso = wave * 1024;                              // staging dest base (u16)

    floatx4 acc[4][4];
#pragma unroll
    for (int i = 0; i < 4; i++)
#pragma unroll
        for (int j = 0; j < 4; j++)
            acc[i][j] = mk4(0.f);

    int swz = (lr >> 1) & 3;
    int rsl = (lq ^ swz) * 8;

    auto stage = [&](int k0, int bsel) {
        u16* Bf = lds + bsel * 16384 + dso;
        gload16(gAh + k0, Bf);          gload16(gAh + q1 + k0, Bf + 512);
        gload16(gAl + k0, Bf + 4096);   gload16(gAl + q1 + k0, Bf + 4608);
        gload16(gBh + k0, Bf + 8192);   gload16(gBh + q1 + k0, Bf + 8704);
        gload16(gBl + k0, Bf + 12288);  gload16(gBl + q1 + k0, Bf + 12800);
    };

    const int NT = K / 32;                              // 80
    stage(0, 0);
    for (int t = 0; t < NT; t++) {
        __syncthreads();               // drains vmcnt(0): buf[t&1] ready; WAR safe
        if (t + 1 < NT) stage((t + 1) * 32, (t + 1) & 1);
        u16* Bc = lds + (t & 1) * 16384;
        bf16x8 ah[4], al[4], bh[4], bl[4];
#pragma unroll
        for (int i = 0; i < 4; i++) {
            int ra = (wr * 64 + i * 16 + lr) * 32 + rsl;
            int rb = (wc * 64 + i * 16 + lr) * 32 + rsl;
            ah[i] = *(const bf16x8*)&Bc[ra];
            al[i] = *(const bf16x8*)&Bc[4096 + ra];
            bh[i] = *(const bf16x8*)&Bc[8192 + rb];
            bl[i] = *(const bf16x8*)&Bc[12288 + rb];
        }
#pragma unroll
        for (int i = 0; i < 4; i++)
#pragma unroll
            for (int j = 0; j < 4; j++) {
                acc[i][j] = __builtin_amdgcn_mfma_f32_16x16x32_bf16(ah[i], bh[j], acc[i][j], 0, 0, 0);
                acc[i][j] = __builtin_amdgcn_mfma_f32_16x16x32_bf16(ah[i], bl[j], acc[i][j], 0, 0, 0);
                acc[i][j] = __builtin_amdgcn_mfma_f32_16x16x32_bf16(al[i], bh[j], acc[i][j], 0, 0, 0);
            }
    }
#pragma unroll
    for (int i = 0; i < 4; i++) {
        int rowb = m0 + wr * 64 + i * 16 + lq * 4;
#pragma unroll
        for (int j = 0; j < 4; j++) {
            int col = n0 + wc * 64 + j * 16 + lr;
#pragma unroll
            for (int r = 0; r < 4; r++)
                C[(size_t)(rowb + r) * HIDDEN + col] = acc[i][j][r];
        }
    }
}

// ------- V-GEMM: same loop, epilogue writes split bf16 directly in the
// key-interleaved transposed layout Vth/Vtl [bh][d(80)][key*(2048)]
// (vtrans fused away). rowb%4==0 so the 4 acc rows -> 4 consecutive dst cols.
__global__ __launch_bounds__(256) void gemm_bt2v(const u16* __restrict__ Ah,
                                                 const u16* __restrict__ Al,
                                                 const u16* __restrict__ Bh,
                                                 const u16* __restrict__ Bl,
                                                 u16* __restrict__ Vth,
                                                 u16* __restrict__ Vtl) {
    __shared__ u16 lds[2 * 16384];
    const int K = HIDDEN;
    int tid  = threadIdx.x;
    int lane = tid & 63;
    int wave = tid >> 6;
    int wr = wave >> 1, wc = wave & 1;
    int lr = lane & 15, lq = lane >> 4;

    int nwgx = gridDim.x;
    int orig = blockIdx.y * nwgx + blockIdx.x;
    int cpx  = (nwgx * gridDim.y) >> 3;
    int wg   = (orig & 7) * cpx + (orig >> 3);
    int n0 = (wg % nwgx) * 128, m0 = (wg / nwgx) * 128;

    int srow = wave * 32 + (lane >> 2);
    int scol = ((lane & 3) ^ ((lane >> 3) & 3)) * 8;
    const u16* gAh = Ah + (size_t)(m0 + srow) * K + scol;
    const u16* gAl = Al + (size_t)(m0 + srow) * K + scol;
    const u16* gBh = Bh + (size_t)(n0 + srow) * K + scol;
    const u16* gBl = Bl + (size_t)(n0 + srow) * K + scol;
    const size_t q1 = (size_t)16 * K;
    int dso = wave * 1024;

    floatx4 acc[4][4];
#pragma unroll
    for (int i = 0; i < 4; i++)
#pragma unroll
        for (int j = 0; j < 4; j++)
            acc[i][j] = mk4(0.f);

    int swz = (lr >> 1) & 3;
    int rsl = (lq ^ swz) * 8;

    auto stage = [&](int k0, int bsel) {
        u16* Bf = lds + bsel * 16384 + dso;
        gload16(gAh + k0, Bf);          gload16(gAh + q1 + k0, Bf + 512);
        gload16(gAl + k0, Bf + 4096);   gload16(gAl + q1 + k0, Bf + 4608);
        gload16(gBh + k0, Bf + 8192);   gload16(gBh + q1 + k0, Bf + 8704);
        gload16(gBl + k0, Bf + 12288);  gload16(gBl + q1 + k0, Bf + 12800);
    };

    const int NT = K / 32;
    stage(0, 0);
    for (int t = 0; t < NT; t++) {
        __syncthreads();
        if (t + 1 < NT) stage((t + 1) * 32, (t + 1) & 1);
        u16* Bc = lds + (t & 1) * 16384;
        bf16x8 ah[4], al[4], bh[4], bl[4];
#pragma unroll
        for (int i = 0; i < 4; i++) {
            int ra = (wr * 64 + i * 16 + lr) * 32 + rsl;
            int rb = (wc * 64 + i * 16 + lr) * 32 + rsl;
            ah[i] = *(const bf16x8*)&Bc[ra];
            al[i] = *(const bf16x8*)&Bc[4096 + ra];
            bh[i] = *(const bf16x8*)&Bc[8192 + rb];
            bl[i] = *(const bf16x8*)&Bc[12288 + rb];
        }
#pragma unroll
        for (int i = 0; i < 4; i++)
#pragma unroll
            for (int j = 0; j < 4; j++) {
                acc[i][j] = __builtin_amdgcn_mfma_f32_16x16x32_bf16(ah[i], bh[j], acc[i][j], 0, 0, 0);
                acc[i][j] = __builtin_amdgcn_mfma_f32_16x16x32_bf16(ah[i], bl[j], acc[i][j], 0, 0, 0);
                acc[i][j] = __builtin_amdgcn_mfma_f32_16x16x32_bf16(al[i], bh[j], acc[i][j], 0, 0, 0);
            }
    }
    // epilogue: split + transposed key-interleaved store
#pragma unroll
    for (int i = 0; i < 4; i++) {
        int rowb = m0 + wr * 64 + i * 16 + lq * 4;      // global V row (b*SEQ+s)
        int b    = rowb >> 11;                           // SEQ = 2048
        int srw  = rowb & (SEQ - 1);
        int kbase = (srw & ~31) + 8 * ((srw >> 2) & 3) + 4 * ((srw >> 4) & 1);
#pragma unroll
        for (int j = 0; j < 4; j++) {
            int col = n0 + wc * 64 + j * 16 + lr;
            int h = col / HD;
            int d = col - h * HD;
            size_t o = ((size_t)(b * NHEADS + h) * HD + d) * SEQ + kbase;
            u16 hh[4], ll[4];
#pragma unroll
            for (int r = 0; r < 4; r++) {
                float f = acc[i][j][r];
                hh[r] = f2bf_bits(f);
                ll[r] = f2bf_bits(f - bf2f(hh[r]));
            }
            *(uint2*)&Vth[o] = *(uint2*)hh;
            *(uint2*)&Vtl[o] = *(uint2*)ll;
        }
    }
}

// ------- fused RoPE + scale + split: src fp32 [row][2560] -> oh/ol bf16 ----------
// thread = (row, head): rope the first 20 cols of the head, scale all 80, split.
// Identical arithmetic order to rope_k followed by split_x(scale).
__global__ __launch_bounds__(256) void rope_split(const float* __restrict__ src,
                                                  const int* __restrict__ pos_ids,
                                                  u16* __restrict__ oh,
                                                  u16* __restrict__ ol,
                                                  float scale) {
    int idx = blockIdx.x * 256 + threadIdx.x;
    int row = idx >> 5;
    int h   = idx & 31;
    float pos = (float)pos_ids[row];
    size_t base = (size_t)row * HIDDEN + h * HD;
    const float* p = src + base;
    float v[80];
#pragma unroll
    for (int c = 0; c < 20; c++) {
        float4 q = *(const float4*)&p[c * 4];
        v[c * 4 + 0] = q.x; v[c * 4 + 1] = q.y;
        v[c * 4 + 2] = q.z; v[c * 4 + 3] = q.w;
    }
#pragma unroll
    for (int i = 0; i < 10; i++) {
        float freq = pos * exp2f(-1.3287712379549449f * (float)i);
        float sn, cs;
        sincosf(freq, &sn, &cs);
        float q1 = v[i], q2 = v[i + 10];
        v[i]      = q1 * cs - q2 * sn;
        v[i + 10] = q2 * cs + q1 * sn;
    }
#pragma unroll
    for (int c = 0; c < 20; c++) {
        u16 hh[4], ll[4];
#pragma unroll
        for (int r = 0; r < 4; r++) {
            float f = v[c * 4 + r] * scale;
            hh[r] = f2bf_bits(f);
            ll[r] = f2bf_bits(f - bf2f(hh[r]));
        }
        *(uint2*)&oh[base + c * 4] = *(uint2*)hh;
        *(uint2*)&ol[base + c * 4] = *(uint2*)ll;
    }
}

// ---------------- MFMA flash attention, v4 (QB=64: 4 waves x 16 queries) ---------
__global__ __launch_bounds__(256, 4) void attn_mfma(const u16* __restrict__ Qh_,
                                                 const u16* __restrict__ Ql_,
                                                 const u16* __restrict__ Kh_,
                                                 const u16* __restrict__ Kl_,
                                                 const u16* __restrict__ Vth_,
                                                 const u16* __restrict__ Vtl_,
                                                 u16* __restrict__ Oh_,
                                                 u16* __restrict__ Ol_) {
    __shared__ u16 lds[20480];          // 2 x 10240 u16 tile buffers = 40960 B

    int tid = threadIdx.x;
    int lane = tid & 63, w = tid >> 6;
    int lr = lane & 15, lq = lane >> 4;
    int bh = blockIdx.x; int b = bh >> 5, h = bh & 31;
    int qblk = (gridDim.y - 1) - blockIdx.y;   // long blocks dispatched first
    int q0 = qblk * QB;
    size_t rowbase = (size_t)b * SEQ;
    size_t hoff = (size_t)h * HD;

    // ---- stage Q (64 rows, hi @0 / lo @6656, pitch 104) -> B-frags ----
    bf16x8 qh[2], ql[2], qta;
    for (int idx = tid; idx < 1280; idx += 256) {
        int buf = idx >= 640; int e = idx - buf * 640;
        int r = e / 10, c = e % 10;
        const u16* src = (buf ? Ql_ : Qh_) +
            (rowbase + q0 + r) * HIDDEN + hoff + c * 8;
        *(int4*)&lds[buf * 6656 + r * 104 + c * 8] = *(const int4*)src;
    }
    __syncthreads();
    {
        int tba = (lq >> 1) ? 6656 : 0;      // qta: lq<2 -> Qh else Ql
        int tcol = 64 + (lq & 1) * 8;
        int lrow = w * 16 + lr;
#pragma unroll
        for (int c = 0; c < 2; c++) {
            qh[c] = *(const bf16x8*)&lds[lrow * 104 + c * 32 + lq * 8];
            ql[c] = *(const bf16x8*)&lds[6656 + lrow * 104 + c * 32 + lq * 8];
        }
        qta = *(const bf16x8*)&lds[tba + lrow * 104 + tcol];
    }
    __syncthreads();

    floatx4 acc[5];
    float mrow = -3.0e38f, lsum = 0.f;
#pragma unroll
    for (int nt = 0; nt < 5; nt++) acc[nt] = mk4(0.f);

    int ntiles = 2 * qblk + 2;
    int qw0 = q0 + w * 16;

    // per-lane staging address components (element units)
    int k0RowOff = (lane >> 3) * HIDDEN + (((lane & 7) ^ (lane >> 3)) * 8);
    int k1RowOff = (lane >> 1) * HIDDEN + 64 + (lane & 1) * 8;
    int vRowOff  = (lane >> 2) * SEQ + ((((lane & 3) ^ ((lane >> 3) & 3))) * 8);
    const u16* kSrc = (w & 1 ? Kl_ : Kh_) + rowbase * HIDDEN + hoff;
    const u16* vSrc = (w == 3 ? Vtl_ : Vth_) + (size_t)bh * HD * SEQ;

    auto stage = [&](int t, int bsel) {
        int k0 = t * 32;
        u16* B = lds + bsel * 10240;
        if (w < 2) {
            const u16* kb = kSrc + (size_t)k0 * HIDDEN;
            u16* d0 = B + w * 2048;
#pragma unroll
            for (int j = 0; j < 4; j++)
                gload16(kb + (size_t)j * 8 * HIDDEN + k0RowOff, d0 + j * 512);
            gload16(kb + k1RowOff, B + 4096 + w * 512);
        } else {
            const u16* vb = vSrc + k0;
            u16* d0 = B + 5120 + (w == 3 ? 2560 : 0);
#pragma unroll
            for (int j = 0; j < 5; j++)
                gload16(vb + (size_t)j * 16 * SEQ + vRowOff, d0 + j * 512);
        }
    };

    // read-side swizzle constants (thread-invariant)
    int ks0 = ((lq) ^ (lr & 7)) * 8;          // K0 c=0 slot
    int ks1 = ((4 + lq) ^ (lr & 7)) * 8;      // K0 c=1 slot
    int k1off  = (lq >> 1) * 512 + (lq & 1) * 8;          // [Kh|Kl] variant
    int k1offb = ((lq >> 1) ^ 1) * 512 + (lq & 1) * 8;    // [Kl|Kh] variant
    int vsl = (lq ^ ((lr >> 1) & 3)) * 8;

    stage(0, 0);

    for (int t = 0; t < ntiles; t++) {
        int k0 = t * 32;
        __syncthreads();                         // drains vmcnt(0): tile t ready
        if (t + 1 < ntiles) stage(t + 1, (t + 1) & 1);
        u16* B = lds + (t & 1) * 10240;
        if (k0 <= qw0 + 15) {
            u16* bK0h = B;
            u16* bK0l = B + 2048;
            u16* bK1  = B + 4096;
            u16* bVh  = B + 5120;
            u16* bVl  = B + 7680;
            __builtin_amdgcn_s_setprio(1);
            // ---- S^T = K Q^T (A=K frag, B=Q frag) ----
            floatx4 s[2];
#pragma unroll
            for (int st = 0; st < 2; st++) {
                int krow = st * 16 + lr;
                bf16x8 kh0 = *(const bf16x8*)&bK0h[krow * 64 + ks0];
                bf16x8 kh1 = *(const bf16x8*)&bK0h[krow * 64 + ks1];
                bf16x8 kl0 = *(const bf16x8*)&bK0l[krow * 64 + ks0];
                bf16x8 kl1 = *(const bf16x8*)&bK0l[krow * 64 + ks1];
                bf16x8 k1f  = *(const bf16x8*)&bK1[krow * 16 + k1off];
                bf16x8 k1fb = *(const bf16x8*)&bK1[krow * 16 + k1offb];
                floatx4 sv = mk4(0.f);
                sv = __builtin_amdgcn_mfma_f32_16x16x32_bf16(kh0, qh[0], sv, 0, 0, 0);
                sv = __builtin_amdgcn_mfma_f32_16x16x32_bf16(kl0, qh[0], sv, 0, 0, 0);
                sv = __builtin_amdgcn_mfma_f32_16x16x32_bf16(kh0, ql[0], sv, 0, 0, 0);
                sv = __builtin_amdgcn_mfma_f32_16x16x32_bf16(kh1, qh[1], sv, 0, 0, 0);
                sv = __builtin_amdgcn_mfma_f32_16x16x32_bf16(kl1, qh[1], sv, 0, 0, 0);
                sv = __builtin_amdgcn_mfma_f32_16x16x32_bf16(kh1, ql[1], sv, 0, 0, 0);
                sv = __builtin_amdgcn_mfma_f32_16x16x32_bf16(k1f,  qta, sv, 0, 0, 0);
                sv = __builtin_amdgcn_mfma_f32_16x16x32_bf16(k1fb, qta, sv, 0, 0, 0);
                s[st] = sv;
            }
            // ---- causal mask (lane q = qw0+lr; keys k0+st*16+lq*4+r) ----
            if (k0 + 31 > qw0) {
                int qmy = qw0 + lr - k0 - lq * 4;   // key_local = st*16+r
#pragma unroll
                for (int r = 0; r < 4; r++) {
                    s[0][r] = (r <= qmy)      ? s[0][r] : -3.0e38f;
                    s[1][r] = (16 + r <= qmy) ? s[1][r] : -3.0e38f;
                }
            }
            // ---- online softmax (per-lane scalar, reduce over lq groups) ----
            float rm = fmaxf(fmaxf(fmaxf(s[0][0], s[0][1]), fmaxf(s[0][2], s[0][3])),
                             fmaxf(fmaxf(s[1][0], s[1][1]), fmaxf(s[1][2], s[1][3])));
            rm = fmaxf(rm, __shfl_xor(rm, 16));
            rm = fmaxf(rm, __shfl_xor(rm, 32));
            int need = rm > mrow + 8.f;
            if (__any(need)) {                 // rescale path (rare: defer-max)
                float mnew = fmaxf(mrow, rm);
                float alpha = __expf(mrow - mnew);
                mrow = mnew;
                lsum *= alpha;
                float at[4];
#pragma unroll
                for (int r = 0; r < 4; r++) at[r] = __shfl(alpha, lq * 4 + r);
#pragma unroll
                for (int nt = 0; nt < 5; nt++)
#pragma unroll
                    for (int r = 0; r < 4; r++) acc[nt][r] *= at[r];
            }
            floatx4 p0 = exp4(s[0] - mk4(mrow));
            floatx4 p1 = exp4(s[1] - mk4(mrow));
            floatx4 ps = p0 + p1;
            float rs = ps[0] + ps[1] + ps[2] + ps[3];
            rs += __shfl_xor(rs, 16);
            rs += __shfl_xor(rs, 32);
            lsum += rs;
            // ---- pack P in-register (matches key-interleaved V layout) ----
            bf16x8 pa;
            pa[0] = (__bf16)p0[0]; pa[1] = (__bf16)p0[1];
            pa[2] = (__bf16)p0[2]; pa[3] = (__bf16)p0[3];
            pa[4] = (__bf16)p1[0]; pa[5] = (__bf16)p1[1];
            pa[6] = (__bf16)p1[2]; pa[7] = (__bf16)p1[3];
            // ---- O += P V ----
#pragma unroll
            for (int nt = 0; nt < 5; nt++) {
                bf16x8 vh = *(const bf16x8*)&bVh[(nt * 16 + lr) * 32 + vsl];
                bf16x8 vl = *(const bf16x8*)&bVl[(nt * 16 + lr) * 32 + vsl];
                acc[nt] = __builtin_amdgcn_mfma_f32_16x16x32_bf16(pa, vh, acc[nt], 0, 0, 0);
                acc[nt] = __builtin_amdgcn_mfma_f32_16x16x32_bf16(pa, vl, acc[nt], 0, 0, 0);
            }
            __builtin_amdgcn_s_setprio(0);
        }
    }
    // ---- epilogue: O /= l, write split-bf16 ----
    {
        float il = 1.f / lsum;
        float inv[4];
#pragma unroll
        for (int r = 0; r < 4; r++) inv[r] = __shfl(il, lq * 4 + r);
#pragma unroll
        for (int nt = 0; nt < 5; nt++) {
#pragma unroll
            for (int r = 0; r < 4; r++) {
                float o = acc[nt][r] * inv[r];
                u16 hh = f2bf_bits(o);
                u16 ll = f2bf_bits(o - bf2f(hh));
                size_t row = rowbase + qw0 + lq * 4 + r;
                Oh_[row * HIDDEN + hoff + nt * 16 + lr] = hh;
                Ol_[row * HIDDEN + hoff + nt * 16 + lr] = ll;
            }
        }
    }
}

extern "C" void kernel_launch(void* const* d_in, const int* in_sizes, int n_in,
                              void* d_out, int out_size, void* d_ws, size_t ws_size,
                              hipStream_t stream) {
    const float* hidden = (const float*)d_in[0];
    const int* pos    = (const int*)d_in[2];
    const float* Wq   = (const float*)d_in[3];
    const float* Wk   = (const float*)d_in[4];
    const float* Wv   = (const float*)d_in[5];
    const float* Wo   = (const float*)d_in[6];

    const size_t NQ = (size_t)MROWS * HIDDEN;          // 10,485,760 elems
    float* ws = (float*)d_ws;
    float* Qb = ws;                                     // [0, NQ) fp32
    float* Kb = ws + NQ;                                // [NQ, 2NQ) fp32
    float* Vb = ws + 2 * NQ;                            // [2NQ, 3NQ) fp32 (region)
    u16* Ah  = (u16*)(ws + 3 * NQ);                     // NQ u16
    u16* Al  = Ah + NQ;                                 // NQ u16
    u16* WTh = Al + NQ;                                 // 2560^2 u16
    u16* WTl = WTh + (size_t)HIDDEN * HIDDEN;           // 2560^2 u16
    // region reuse (194 MB total footprint):
    u16* Vth = (u16*)Vb;              // V-GEMM writes split V here (Vb never fp32)
    u16* Vtl = Vth + NQ;
    u16* Qh  = Ah;                    // after QKV GEMMs, Ah/Al free
    u16* Ql  = Al;
    u16* Kh  = (u16*)Qb;              // after rope_split(Q), Qb free
    u16* Kl  = Kh + NQ;
    u16* Oh  = (u16*)Kb;              // after rope_split(K), Kb free
    u16* Ol  = Oh + NQ;

    const float SC = 0.11180339887498949f;              // 1/sqrt(80)

    dim3 blk(256);
    dim3 wgrid(HIDDEN / 64, HIDDEN / 64);
    dim3 ggrid(HIDDEN / 128, MROWS / 128);

    split_x<<<dim3(NQ / 1024), blk, 0, stream>>>(hidden, Ah, Al, 1.f);
    split_wt<<<wgrid, blk, 0, stream>>>(Wq, WTh, WTl);
    gemm_bt2<<<ggrid, blk, 0, stream>>>(Ah, Al, WTh, WTl, Qb);
    split_wt<<<wgrid, blk, 0, stream>>>(Wk, WTh, WTl);
    gemm_bt2<<<ggrid, blk, 0, stream>>>(Ah, Al, WTh, WTl, Kb);
    split_wt<<<wgrid, blk, 0, stream>>>(Wv, WTh, WTl);
    gemm_bt2v<<<ggrid, blk, 0, stream>>>(Ah, Al, WTh, WTl, Vth, Vtl);
    rope_split<<<dim3(MROWS * NHEADS / 256), blk, 0, stream>>>(Qb, pos, Qh, Ql, SC);
    rope_split<<<dim3(MROWS * NHEADS / 256), blk, 0, stream>>>(Kb, pos, Kh, Kl, 1.f);
    attn_mfma<<<dim3(BATCH * NHEADS, SEQ / QB), blk, 0, stream>>>(Qh, Ql, Kh, Kl,
                                                                  Vth, Vtl, Oh, Ol);
    split_wt<<<wgrid, blk, 0, stream>>>(Wo, WTh, WTl);
    gemm_bt2<<<ggrid, blk, 0, stream>>>(Oh, Ol, WTh, WTl, (float*)d_out);
}